// Round 2
// baseline (446.551 us; speedup 1.0000x reference)
//
#include <hip/hip_runtime.h>
#include <hip/hip_bf16.h>

#define NN 8192
#define DIN 128
#define DOUT 128

typedef __bf16 bf16;
typedef __bf16 bf16x8 __attribute__((ext_vector_type(8)));
typedef float f32x4 __attribute__((ext_vector_type(4)));

// ---- K1: rowsum -> dinv[i] = rsqrt(sum+eps), AND adjh = bf16(adj). -------
// One pass over adj (256 MB read, 128 MB write). The bf16 truncation is
// numerically identical to what k3's fragment build already did.
__global__ __launch_bounds__(256) void k1_rowsum(const float* __restrict__ adj,
                                                 float* __restrict__ dinv,
                                                 bf16* __restrict__ adjh) {
    int row = blockIdx.x;
    int t   = threadIdx.x;
    const float* rp = adj  + (size_t)row * NN;
    bf16*        hp = adjh + (size_t)row * NN;
    float s = 0.f;
    #pragma unroll
    for (int i = 0; i < 4; ++i) {
        int base = i * 2048 + t * 8;          // 32 B contiguous per lane
        float4 a = *reinterpret_cast<const float4*>(rp + base);
        float4 b = *reinterpret_cast<const float4*>(rp + base + 4);
        s += ((a.x + a.y) + (a.z + a.w)) + ((b.x + b.y) + (b.z + b.w));
        bf16x8 h = { (bf16)a.x, (bf16)a.y, (bf16)a.z, (bf16)a.w,
                     (bf16)b.x, (bf16)b.y, (bf16)b.z, (bf16)b.w };
        *reinterpret_cast<bf16x8*>(hp + base) = h;   // 16 B coalesced store
    }
    #pragma unroll
    for (int off = 32; off > 0; off >>= 1) s += __shfl_down(s, off, 64);
    __shared__ float r4[4];
    if ((t & 63) == 0) r4[t >> 6] = s;
    __syncthreads();
    if (t == 0) dinv[row] = rsqrtf(((r4[0] + r4[1]) + (r4[2] + r4[3])) + 1e-6f);
}

// ---- K2: z = x @ W^T;  yT[c][j] = bf16(dinv[j] * z[j][c])  (transposed) --
__global__ __launch_bounds__(256) void k2_xwT(const float* __restrict__ x,
                                              const float* __restrict__ W,
                                              const float* __restrict__ dinv,
                                              bf16* __restrict__ yT) {
    __shared__ float Wl[128 * 132];
    __shared__ float xl[32 * 132];
    __shared__ float dl[32];
    int t  = threadIdx.x;
    int i0 = blockIdx.x * 32;
    if (t < 32) dl[t] = dinv[i0 + t];
    #pragma unroll
    for (int s = 0; s < 16; ++s) {
        int i  = t + s * 256;
        int o  = i >> 5;
        int c4 = i & 31;
        *reinterpret_cast<float4*>(&Wl[o * 132 + c4 * 4]) =
            *reinterpret_cast<const float4*>(W + o * 128 + c4 * 4);
    }
    #pragma unroll
    for (int s = 0; s < 4; ++s) {
        int i   = t + s * 256;
        int row = i >> 5;
        int c4  = i & 31;
        *reinterpret_cast<float4*>(&xl[row * 132 + c4 * 4]) =
            *reinterpret_cast<const float4*>(x + (size_t)(i0 + row) * DIN + c4 * 4);
    }
    __syncthreads();
    int o = t & 127;          // output feature (column of z, row of yT)
    int g = t >> 7;           // row group: rows g*16 .. g*16+15
    float acc[16] = {};
    for (int c4 = 0; c4 < 32; ++c4) {
        float4 w4 = *reinterpret_cast<const float4*>(&Wl[o * 132 + c4 * 4]);
        #pragma unroll
        for (int r = 0; r < 16; ++r) {
            float4 h4 = *reinterpret_cast<const float4*>(&xl[(g * 16 + r) * 132 + c4 * 4]);
            acc[r] += h4.x * w4.x + h4.y * w4.y + h4.z * w4.z + h4.w * w4.w;
        }
    }
    bf16x8 o0, o1;
    #pragma unroll
    for (int r = 0; r < 8; ++r) o0[r] = (bf16)(acc[r] * dl[g * 16 + r]);
    #pragma unroll
    for (int r = 0; r < 8; ++r) o1[r] = (bf16)(acc[8 + r] * dl[g * 16 + 8 + r]);
    bf16* dst = yT + (size_t)o * NN + i0 + g * 16;
    *reinterpret_cast<bf16x8*>(dst)     = o0;
    *reinterpret_cast<bf16x8*>(dst + 8) = o1;
}

// ---- K3: partial[split] = dinv[i] * (adjh[i, ksplit] @ y[ksplit, :]) -----
// A-operand now bf16 from adjh: half the bytes, zero cvt VALU work, one
// 16 B load per lane per k-step. Row-groups processed in DESCENDING order
// so k1's most-recently-written adjh rows (L3-resident) are consumed first.
#define KR3 512
#define LDB3 520   // 1040 B row stride: 16B-aligned, slot-disjoint b128 reads

__global__ __launch_bounds__(512, 2) void k3_spmm(const bf16* __restrict__ adjh,
                                                  const bf16* __restrict__ yT,
                                                  const float* __restrict__ dinv,
                                                  float* __restrict__ part) {
    __shared__ bf16 BL[128 * LDB3];   // 130 KB
    int t     = threadIdx.x;
    int split = blockIdx.x & 3;
    int mg    = 63 - (blockIdx.x >> 2);   // reversed: L3-hot rows first
    int m0    = mg * 128;
    int kbase = split * 2048;

    int wave = t >> 6, lane = t & 63;
    int mrow = lane & 15, quad = lane >> 4;
    int wm0  = m0 + wave * 16;        // this wave's 16-row strip

    f32x4 acc[8] = {};

    for (int cc = 0; cc < 4; ++cc) {
        int kc = kbase + cc * KR3;
        if (cc) __syncthreads();      // prior chunk's ds_reads done before restage
        for (int i = t; i < 128 * 64; i += 512) {
            int c = i >> 6, ch = i & 63;
            *reinterpret_cast<uint4*>(&BL[c * LDB3 + ch * 8]) =
                *reinterpret_cast<const uint4*>(yT + (size_t)c * NN + kc + ch * 8);
        }
        __syncthreads();

        const bf16* ap = adjh + (size_t)(wm0 + mrow) * NN + kc + quad * 8;
        // 2-deep software pipeline on adjh: consume kk, hold kk+1, issue kk+2
        bf16x8 cfr = *reinterpret_cast<const bf16x8*>(ap);
        bf16x8 nfr = *reinterpret_cast<const bf16x8*>(ap + 32);
        #pragma unroll
        for (int kk = 0; kk < KR3 / 32; ++kk) {
            bf16x8 bf[8];
            int boff = kk * 32 + quad * 8;
            #pragma unroll
            for (int nt = 0; nt < 8; ++nt)
                bf[nt] = *reinterpret_cast<const bf16x8*>(&BL[(nt * 16 + mrow) * LDB3 + boff]);
            int pk = (kk < KR3 / 32 - 2) ? (kk + 2) * 32 : 0;   // const-folded
            bf16x8 ffr = *reinterpret_cast<const bf16x8*>(ap + pk);
            #pragma unroll
            for (int nt = 0; nt < 8; ++nt)
                acc[nt] = __builtin_amdgcn_mfma_f32_16x16x32_bf16(cfr, bf[nt], acc[nt], 0, 0, 0);
            cfr = nfr; nfr = ffr;
        }
    }

    // epilogue: plain stores of this split's 128x128 tile, scaled by dinv[row]
    f32x4 dv = *reinterpret_cast<const f32x4*>(dinv + wm0 + quad * 4);
    float* pout = part + (size_t)split * (NN * DOUT) + (size_t)wm0 * DOUT;
    #pragma unroll
    for (int nt = 0; nt < 8; ++nt) {
        int col = nt * 16 + mrow;
        #pragma unroll
        for (int r = 0; r < 4; ++r)
            pout[(quad * 4 + r) * DOUT + col] = acc[nt][r] * dv[r];
    }
}

// ---- K4: out = bias + sum over 4 split partials. 20 MB stream. -----------
__global__ __launch_bounds__(256) void k4_reduce(const float* __restrict__ part,
                                                 const float* __restrict__ bias,
                                                 float* __restrict__ out) {
    size_t g = (size_t)blockIdx.x * 256 + threadIdx.x;   // float4 index
    float4 s = *reinterpret_cast<const float4*>(bias + (g & 31) * 4);
    #pragma unroll
    for (int sp = 0; sp < 4; ++sp) {
        float4 p = *reinterpret_cast<const float4*>(part + (size_t)sp * NN * DOUT + g * 4);
        s.x += p.x; s.y += p.y; s.z += p.z; s.w += p.w;
    }
    *reinterpret_cast<float4*>(out + g * 4) = s;
}

extern "C" void kernel_launch(void* const* d_in, const int* in_sizes, int n_in,
                              void* d_out, int out_size, void* d_ws, size_t ws_size,
                              hipStream_t stream) {
    const float* x   = (const float*)d_in[0];
    const float* adj = (const float*)d_in[1];
    const float* W   = (const float*)d_in[2];
    const float* b   = (const float*)d_in[3];
    float* out = (float*)d_out;
    char* ws = (char*)d_ws;
    float* dinv = (float*)ws;                   // 32 KB  @ 0
    bf16*  yT   = (bf16*)(ws + (1u << 20));     // 2 MB   @ 1 MB
    float* part = (float*)(ws + (4u << 20));    // 16 MB  @ 4 MB
    bf16*  adjh = (bf16*)(ws + (32u << 20));    // 128 MB @ 32 MB

    k1_rowsum<<<NN, 256, 0, stream>>>(adj, dinv, adjh);
    k2_xwT   <<<NN / 32, 256, 0, stream>>>(x, W, dinv, yT);
    k3_spmm  <<<4 * (NN / 128), 512, 0, stream>>>(adjh, yT, dinv, part);
    k4_reduce<<<(NN * DOUT / 4) / 256, 256, 0, stream>>>(part, b, out);
}